// Round 3
// baseline (219.079 us; speedup 1.0000x reference)
//
#include <hip/hip_runtime.h>
#include <hip/hip_bf16.h>
#include <hip/hip_fp16.h>

#define N_NODES 50000
#define N_EDGES 640000
#define E_TOT   690000   // edges + self-loops
#define CH      128
#define ROWPAD  50176    // padded rows for H/AS/AD/X2 (128-row GEMM tiles overrun)
#define GEMMB   391      // ceil(50000 / 128) row-tiles of 128
#define EBLK    2048     // edges per hist/bucket block
#define NEB     337      // ceil(E_TOT / EBLK)
#define NBUCK   196      // ceil(N_NODES / 256)
#define MTP     344      // MT row pitch (>= NEB)

typedef __attribute__((ext_vector_type(8))) short short8;
typedef __attribute__((ext_vector_type(4))) float float4v;

static __device__ __forceinline__ float bf2f(unsigned short u) {
  return __uint_as_float(((unsigned)u) << 16);
}
static __device__ __forceinline__ unsigned short f2bf(float f) {
  unsigned u = __float_as_uint(f);
  return (unsigned short)((u + 0x7fffu + ((u >> 16) & 1u)) >> 16);
}

static __device__ __forceinline__ void load_edge(const int* __restrict__ ei,
                                                 int e, int i64, int& s, int& d)
{
  if (e >= N_EDGES) { s = d = e - N_EDGES; return; }
  if (i64) { s = ei[2 * (size_t)e]; d = ei[2 * ((size_t)N_EDGES + e)]; }
  else     { s = ei[e];             d = ei[N_EDGES + e]; }
}

static __device__ __forceinline__ short8 load_bf8(const void* __restrict__ X,
                                                  size_t off, int f32)
{
  if (!f32) return *(const short8*)((const unsigned short*)X + off);
  const float4* p = (const float4*)((const float*)X + off);
  float4 u = p[0], v = p[1];
  short8 r;
  r[0] = (short)f2bf(u.x); r[1] = (short)f2bf(u.y);
  r[2] = (short)f2bf(u.z); r[3] = (short)f2bf(u.w);
  r[4] = (short)f2bf(v.x); r[5] = (short)f2bf(v.y);
  r[6] = (short)f2bf(v.z); r[7] = (short)f2bf(v.w);
  return r;
}

// ---- prep: fused dtype-detect + W transpose + Ba ------------------------
__global__ __launch_bounds__(256) void k_prep(
    const void* __restrict__ W1, const void* __restrict__ W2,
    const void* __restrict__ as1, const void* __restrict__ ad1,
    const void* __restrict__ as2, const void* __restrict__ ad2,
    unsigned short* __restrict__ Wt1, unsigned short* __restrict__ Wt2,
    unsigned short* __restrict__ Ba1, unsigned short* __restrict__ Ba2,
    const unsigned short* __restrict__ x16,
    const unsigned int* __restrict__ eiw,
    int* __restrict__ flags)
{
  int b = blockIdx.x, t = threadIdx.x;
  __shared__ int sf, si;
  if (t == 0) { sf = 0; si = 1; }
  __syncthreads();
  int bad = 0;
  for (int i = t; i < 4096; i += 256) {
    float v = bf2f(x16[i]);
    if (!(v == v) || fabsf(v) > 100.f) bad = 1;
  }
  if (bad) atomicOr(&sf, 1);
  if (b == 0 && t < 128 && eiw[2 * t + 1] != 0u) atomicAnd(&si, 0);
  __syncthreads();
  int f32 = sf;
  if (b == 0 && t == 0) { flags[0] = sf; flags[1] = si; }

  if (b < 8) {
    int g = b * 256 + t;          // 0..2047
    int l = g >> 10;
    int rem = g & 1023;
    int k = rem >> 3, n = rem & 7;
    const void* W  = l ? W2 : W1;
    const void* av = (n < 4) ? (l ? as2 : as1) : (l ? ad2 : ad1);
    int h = n & 3;
    float sum = 0.f;
    for (int c = 0; c < 32; c++) {
      float w = f32 ? ((const float*)W)[k * 128 + h * 32 + c]
                    : bf2f(((const unsigned short*)W)[k * 128 + h * 32 + c]);
      float a = f32 ? ((const float*)av)[h * 32 + c]
                    : bf2f(((const unsigned short*)av)[h * 32 + c]);
      sum += w * a;
    }
    unsigned short* Ba = l ? Ba2 : Ba1;
    Ba[n * 128 + k] = f2bf(sum);
    Ba[(8 + (rem >> 7)) * 128 + (rem & 127)] = 0;   // zero rows 8..15
  } else {
    int b2 = b - 8;
    int l = b2 >> 7, c = b2 & 127;
    if (t < 128) {
      const void* W = l ? W2 : W1;
      unsigned short* Wt = l ? Wt2 : Wt1;
      Wt[c * 128 + t] = f32 ? f2bf(((const float*)W)[t * 128 + c])
                            : ((const unsigned short*)W)[t * 128 + c];
    }
  }
}

// ---- shared GEMM body: 128-row tiles, each B-frag feeds 2 MFMAs ---------
struct SmemG { unsigned short WB[144][136]; };

static __device__ __forceinline__ void gemm_body(
    SmemG& sm, int bx,
    const void* __restrict__ X,
    const unsigned short* __restrict__ Wt_g,
    const unsigned short* __restrict__ Ba_g,
    unsigned short* __restrict__ H, float* __restrict__ AS,
    float* __restrict__ AD, int nrows, int xf32)
{
  int tid = threadIdx.x;
#pragma unroll
  for (int i = 0; i < 8; i++) {
    int j = i * 256 + tid;        // 2048 16B chunks of W^T
    int c = j >> 4, k8 = j & 15;
    *(short8*)&sm.WB[c][k8 * 8] = *(const short8*)(Wt_g + c * 128 + k8 * 8);
  }
  {
    int n = tid >> 4, k8 = tid & 15;   // Ba rows 128..143 (8..15 zeroed)
    *(short8*)&sm.WB[128 + n][k8 * 8] = *(const short8*)(Ba_g + n * 128 + k8 * 8);
  }
  __syncthreads();
  int wave = tid >> 6, lane = tid & 63;
  int R0 = (bx * 4 + wave) * 32;
  if (R0 >= nrows) return;
  int m = lane & 15, quad = lane >> 4;
  int rA = R0 + m;        if (rA >= nrows) rA = nrows - 1;   // clamp: last tile only
  int rB = R0 + 16 + m;   if (rB >= nrows) rB = nrows - 1;
  size_t aA = (size_t)rA * CH + quad * 8;
  size_t aB = (size_t)rB * CH + quad * 8;
  float4v acc[2][8];
  float4v accA[2];
#pragma unroll
  for (int hf = 0; hf < 2; hf++) {
    accA[hf] = (float4v){0.f, 0.f, 0.f, 0.f};
#pragma unroll
    for (int ct = 0; ct < 8; ct++) acc[hf][ct] = (float4v){0.f, 0.f, 0.f, 0.f};
  }
#pragma unroll
  for (int kb = 0; kb < 4; kb++) {
    short8 a0 = load_bf8(X, aA + kb * 32, xf32);
    short8 a1 = load_bf8(X, aB + kb * 32, xf32);
#pragma unroll
    for (int ct = 0; ct < 8; ct++) {
      short8 bb = *(const short8*)&sm.WB[ct * 16 + m][kb * 32 + quad * 8];
      acc[0][ct] = __builtin_amdgcn_mfma_f32_16x16x32_bf16(a0, bb, acc[0][ct], 0, 0, 0);
      acc[1][ct] = __builtin_amdgcn_mfma_f32_16x16x32_bf16(a1, bb, acc[1][ct], 0, 0, 0);
    }
    short8 bA = *(const short8*)&sm.WB[128 + m][kb * 32 + quad * 8];
    accA[0] = __builtin_amdgcn_mfma_f32_16x16x32_bf16(a0, bA, accA[0], 0, 0, 0);
    accA[1] = __builtin_amdgcn_mfma_f32_16x16x32_bf16(a1, bA, accA[1], 0, 0, 0);
  }
#pragma unroll
  for (int hf = 0; hf < 2; hf++) {
    int rbase = R0 + hf * 16 + quad * 4;
#pragma unroll
    for (int ct = 0; ct < 8; ct++) {
      int col = ct * 16 + m;
#pragma unroll
      for (int r = 0; r < 4; r++)
        H[(size_t)(rbase + r) * CH + col] = __half_as_ushort(__float2half(acc[hf][ct][r]));
    }
    if (m < 4) {
#pragma unroll
      for (int r = 0; r < 4; r++)
        AS[(size_t)(rbase + r) * 4 + m] = accA[hf][r];
    } else if (m < 8) {
#pragma unroll
      for (int r = 0; r < 4; r++)
        AD[(size_t)(rbase + r) * 4 + (m - 4)] = accA[hf][r];
    }
  }
}

// layer-2 GEMM (standalone; X2 always bf16)
__global__ __launch_bounds__(256, 2) void k_gemm(
    const void* __restrict__ X,
    const unsigned short* __restrict__ Wt_g,
    const unsigned short* __restrict__ Ba_g,
    unsigned short* __restrict__ H, float* __restrict__ AS, float* __restrict__ AD,
    int nrows)
{
  __shared__ SmemG sm;
  gemm_body(sm, blockIdx.x, X, Wt_g, Ba_g, H, AS, AD, nrows, 0);
}

// layer-1 GEMM fused with bucket histogram (pass A)
__global__ __launch_bounds__(256, 2) void k_gemm_hist(
    const void* __restrict__ X,
    const unsigned short* __restrict__ Wt_g,
    const unsigned short* __restrict__ Ba_g,
    unsigned short* __restrict__ H, float* __restrict__ AS, float* __restrict__ AD,
    int nrows, const int* __restrict__ ei, int* __restrict__ MT,
    const int* __restrict__ flags)
{
  __shared__ SmemG sm;          // gemm blocks only
  __shared__ int hist[NBUCK];   // hist blocks only
  if (blockIdx.x >= GEMMB) {
    int b = blockIdx.x - GEMMB;
    int t = threadIdx.x;
    if (t < NBUCK) hist[t] = 0;
    __syncthreads();
    int i64 = flags[1];
    int base = b * EBLK;
#pragma unroll
    for (int k = 0; k < 8; k++) {
      int e = base + k * 256 + t;
      if (e < E_TOT) {
        int s, d;
        load_edge(ei, e, i64, s, d);
        atomicAdd(&hist[d >> 8], 1);
      }
    }
    __syncthreads();
    if (t < NBUCK) MT[t * MTP + b] = hist[t];
    return;
  }
  gemm_body(sm, blockIdx.x, X, Wt_g, Ba_g, H, AS, AD, nrows, flags[0]);
}

// pass B: exclusive-scan each MT row; T[q]=total
__global__ __launch_bounds__(512) void k_rowscan(int* __restrict__ MT,
                                                 int* __restrict__ T)
{
  __shared__ int sh[512];
  int q = blockIdx.x, t = threadIdx.x;
  int v = (t < NEB) ? MT[q * MTP + t] : 0;
  sh[t] = v;
  __syncthreads();
  for (int off = 1; off < 512; off <<= 1) {
    int u = (t >= off) ? sh[t - off] : 0;
    __syncthreads();
    sh[t] += u;
    __syncthreads();
  }
  if (t < NEB) MT[q * MTP + t] = sh[t] - v;
  if (t == NEB - 1) T[q] = sh[t];
}

// pass B2: exclusive-scan bucket totals
__global__ __launch_bounds__(256) void k_bscan(const int* __restrict__ T,
                                               int* __restrict__ BB)
{
  __shared__ int sh[256];
  int t = threadIdx.x;
  int v = (t < NBUCK) ? T[t] : 0;
  sh[t] = v;
  __syncthreads();
  for (int off = 1; off < 256; off <<= 1) {
    int u = (t >= off) ? sh[t - off] : 0;
    __syncthreads();
    sh[t] += u;
    __syncthreads();
  }
  if (t < NBUCK) BB[t] = sh[t] - v;
  if (t == NBUCK - 1) BB[NBUCK] = sh[t];
}

// pass C: scatter edges into bucket-ordered ebuf (LDS cursors)
// packed: word = (s << 8) | (d & 255)  — s < 65536, bucket-local d in low byte
__global__ __launch_bounds__(256) void k_bucket(
    const int* __restrict__ ei, const int* __restrict__ MT,
    const int* __restrict__ BB, unsigned int* __restrict__ ebuf,
    const int* __restrict__ flags)
{
  __shared__ int cur[NBUCK];
  int b = blockIdx.x, t = threadIdx.x;
  if (t < NBUCK) cur[t] = BB[t] + MT[t * MTP + b];
  __syncthreads();
  int i64 = flags[1];
  int base = b * EBLK;
#pragma unroll
  for (int k = 0; k < 8; k++) {
    int e = base + k * 256 + t;
    if (e < E_TOT) {
      int s, d;
      load_edge(ei, e, i64, s, d);
      int pos = atomicAdd(&cur[d >> 8], 1);   // LDS atomic
      ebuf[pos] = ((unsigned)s << 8) | (unsigned)(d & 255);
    }
  }
}

// pass D: per-bucket fine CSR -> rpdeg (int2) + ushort csr
__global__ __launch_bounds__(256) void k_fine(
    const unsigned int* __restrict__ ebuf, const int* __restrict__ BB,
    int2* __restrict__ rpdeg, unsigned short* __restrict__ csr)
{
  __shared__ int cnt[256], sh[256], cur[256];
  int q = blockIdx.x, t = threadIdx.x;
  int lo = BB[q], hi = BB[q + 1];
  cnt[t] = 0;
  __syncthreads();
  for (int i = lo + t; i < hi; i += 256)
    atomicAdd(&cnt[ebuf[i] & 255u], 1);
  __syncthreads();
  int v = cnt[t];
  sh[t] = v;
  __syncthreads();
  for (int off = 1; off < 256; off <<= 1) {
    int u = (t >= off) ? sh[t - off] : 0;
    __syncthreads();
    sh[t] += u;
    __syncthreads();
  }
  int lp = sh[t] - v;
  int n = (q << 8) + t;
  if (n < N_NODES) rpdeg[n] = make_int2(lo + lp, v);
  cur[t] = lo + lp;
  __syncthreads();
  for (int i = lo + t; i < hi; i += 256) {
    unsigned p = ebuf[i];
    int slot = atomicAdd(&cur[p & 255u], 1);   // LDS atomic
    csr[slot] = (unsigned short)(p >> 8);
  }
}

// ---- fused gather-aggregate + softmax + epilogue ------------------------
// one fully-predicated 16-wide round: no 4/1-wide tails; padding slots clamp
// to the node's last edge (same cache line, ~free) with zero softmax weight.
__global__ __launch_bounds__(256) void k_agg(
    const int2* __restrict__ rpdeg,
    const unsigned short* __restrict__ csr,
    const __half* __restrict__ H,
    const float* __restrict__ AS, const float* __restrict__ AD,
    const void* __restrict__ b, void* __restrict__ Y,
    const int* __restrict__ flags, int layer)
{
  int tid = threadIdx.x;
  int node = blockIdx.x * 4 + (tid >> 6);
  if (node >= N_NODES) return;
  int lane = tid & 63;
  int h = lane >> 4;
  int c0 = 2 * lane;
  int2 rd = rpdeg[node];
  int start = rd.x, dg = rd.y;
  float adh = AD[(size_t)node * 4 + h];
  const __half2* __restrict__ H2 = (const __half2*)H;
  float accx = 0.f, accy = 0.f, den = 0.f;
  int last = start + dg - 1;      // dg >= 1 always (self-loop)
  for (int j = 0; j < dg; j += 16) {
    int sI[16];
#pragma unroll
    for (int u = 0; u < 16; u++) {
      int idx = start + j + u;
      sI[u] = (int)csr[idx <= last ? idx : last];
    }
    float2 vV[16];
#pragma unroll
    for (int u = 0; u < 16; u++)
      vV[u] = __half22float2(H2[sI[u] * 64 + lane]);
    float eV[16];
#pragma unroll
    for (int u = 0; u < 16; u++)
      eV[u] = AS[sI[u] * 4 + h] + adh;
#pragma unroll
    for (int u = 0; u < 16; u++) {
      float x = eV[u] > 0.f ? eV[u] : 0.2f * eV[u];
      float ex = (j + u < dg) ? __expf(x) : 0.f;
      accx += ex * vV[u].x;
      accy += ex * vV[u].y;
      den  += ex;
    }
  }
  float inv = 1.f / (den + 1e-16f);
  int f32 = flags[0];
  float b0 = f32 ? ((const float*)b)[c0]     : bf2f(((const unsigned short*)b)[c0]);
  float b1 = f32 ? ((const float*)b)[c0 + 1] : bf2f(((const unsigned short*)b)[c0 + 1]);
  float r0 = accx * inv + b0;
  float r1 = accy * inv + b1;
  size_t o = (size_t)node * CH + c0;
  if (layer == 1) {                 // relu + bf16 -> X2
    r0 = r0 > 0.f ? r0 : 0.f;
    r1 = r1 > 0.f ? r1 : 0.f;
    ushort2 w; w.x = f2bf(r0); w.y = f2bf(r1);
    *(ushort2*)((unsigned short*)Y + o) = w;
  } else if (f32) {
    float2 w; w.x = r0; w.y = r1;
    *(float2*)((float*)Y + o) = w;
  } else {
    ushort2 w; w.x = f2bf(r0); w.y = f2bf(r1);
    *(ushort2*)((unsigned short*)Y + o) = w;
  }
}

extern "C" void kernel_launch(void* const* d_in, const int* in_sizes, int n_in,
                              void* d_out, int out_size, void* d_ws, size_t ws_size,
                              hipStream_t stream)
{
  const void* x   = d_in[0];
  const int*  ei  = (const int*)d_in[1];
  const void* W1  = d_in[2];
  const void* as1 = d_in[3];
  const void* ad1 = d_in[4];
  const void* b1  = d_in[5];
  const void* W2  = d_in[6];
  const void* as2 = d_in[7];
  const void* ad2 = d_in[8];
  const void* b2  = d_in[9];

  char* ws = (char*)d_ws;
  unsigned short* H   = (unsigned short*)(ws);             // 50176*128 fp16 = 12,845,056 B
  float*  AS          = (float*)(ws + 12845056);           //    802,816 B
  float*  AD          = (float*)(ws + 13647872);           //    802,816 B
  unsigned short* X2  = (unsigned short*)(ws + 14450688);  // 12,845,056 B
  int2*   rpdeg       = (int2*)(ws + 27295744);            //    400,000 B
  unsigned short* csr = (unsigned short*)(ws + 27697152);  //  1,380,000 B
  int*    MT          = (int*)(ws + 29080000);             //    269,696 B
  int*    T           = (int*)(ws + 29350000);             //        784 B
  int*    BB          = (int*)(ws + 29351000);             //        788 B
  int*    flags       = (int*)(ws + 29352000);             //         64 B
  unsigned int* ebuf  = (unsigned int*)(ws + 29353216);    //  2,760,000 B
  unsigned short* Wt1 = (unsigned short*)(ws + 32120000);  //     32,768 B
  unsigned short* Wt2 = (unsigned short*)(ws + 32152768);  //     32,768 B
  unsigned short* Ba1 = (unsigned short*)(ws + 32185536);  //      4,096 B
  unsigned short* Ba2 = (unsigned short*)(ws + 32189632);  //      4,096 B

  const int agg_blocks = (N_NODES + 3) / 4;                // 1 wave per node

  // prep: detect + W transpose + Ba (fused, 1 launch)
  k_prep<<<264, 256, 0, stream>>>(W1, W2, as1, ad1, as2, ad2,
                                  Wt1, Wt2, Ba1, Ba2,
                                  (const unsigned short*)x,
                                  (const unsigned int*)ei, flags);

  // layer-1 GEMM (128-row tiles) overlapped with bucket histogram (pass A)
  k_gemm_hist<<<GEMMB + NEB, 256, 0, stream>>>(
      x, Wt1, Ba1, H, AS, AD, N_NODES, ei, MT, flags);

  // CSR build, atomic-free in global memory (LDS cursors only)
  k_rowscan<<<NBUCK, 512, 0, stream>>>(MT, T);
  k_bscan  <<<1, 256, 0, stream>>>(T, BB);
  k_bucket <<<NEB, 256, 0, stream>>>(ei, MT, BB, ebuf, flags);
  k_fine   <<<NBUCK, 256, 0, stream>>>(ebuf, BB, rpdeg, csr);

  // layer 1 aggregate
  k_agg<<<agg_blocks, 256, 0, stream>>>(rpdeg, csr,
                                        (const __half*)H, AS, AD,
                                        b1, X2, flags, 1);

  // layer 2
  k_gemm<<<GEMMB, 256, 0, stream>>>(X2, Wt2, Ba2, H, AS, AD, N_NODES);
  k_agg<<<agg_blocks, 256, 0, stream>>>(rpdeg, csr,
                                        (const __half*)H, AS, AD,
                                        b2, d_out, flags, 2);
}

// Round 4
// 212.247 us; speedup vs baseline: 1.0322x; 1.0322x over previous
//
#include <hip/hip_runtime.h>
#include <hip/hip_bf16.h>
#include <hip/hip_fp16.h>

#define N_NODES 50000
#define N_EDGES 640000
#define E_TOT   690000   // edges + self-loops
#define CH      128
#define ROWPAD  50176    // padded rows for H/AS/AD/X2 (128-row GEMM tiles overrun)
#define GEMMB   391      // ceil(50000 / 128) row-tiles of 128
#define EBLK    2048     // edges per scatter block
#define NEB     337      // ceil(E_TOT / EBLK)
#define NBUCK   196      // ceil(N_NODES / 256)
#define CAP     4608     // bucket capacity (mean 3533, sigma 57 -> >18 sigma margin)

typedef __attribute__((ext_vector_type(8))) short short8;
typedef __attribute__((ext_vector_type(4))) float float4v;

static __device__ __forceinline__ float bf2f(unsigned short u) {
  return __uint_as_float(((unsigned)u) << 16);
}
static __device__ __forceinline__ unsigned short f2bf(float f) {
  unsigned u = __float_as_uint(f);
  return (unsigned short)((u + 0x7fffu + ((u >> 16) & 1u)) >> 16);
}

static __device__ __forceinline__ void load_edge(const int* __restrict__ ei,
                                                 int e, int i64, int& s, int& d)
{
  if (e >= N_EDGES) { s = d = e - N_EDGES; return; }
  if (i64) { s = ei[2 * (size_t)e]; d = ei[2 * ((size_t)N_EDGES + e)]; }
  else     { s = ei[e];             d = ei[N_EDGES + e]; }
}

static __device__ __forceinline__ short8 load_bf8(const void* __restrict__ X,
                                                  size_t off, int f32)
{
  if (!f32) return *(const short8*)((const unsigned short*)X + off);
  const float4* p = (const float4*)((const float*)X + off);
  float4 u = p[0], v = p[1];
  short8 r;
  r[0] = (short)f2bf(u.x); r[1] = (short)f2bf(u.y);
  r[2] = (short)f2bf(u.z); r[3] = (short)f2bf(u.w);
  r[4] = (short)f2bf(v.x); r[5] = (short)f2bf(v.y);
  r[6] = (short)f2bf(v.z); r[7] = (short)f2bf(v.w);
  return r;
}

// ---- prep: fused dtype-detect + W transpose + Ba + gcur init -----------
__global__ __launch_bounds__(256) void k_prep(
    const void* __restrict__ W1, const void* __restrict__ W2,
    const void* __restrict__ as1, const void* __restrict__ ad1,
    const void* __restrict__ as2, const void* __restrict__ ad2,
    unsigned short* __restrict__ Wt1, unsigned short* __restrict__ Wt2,
    unsigned short* __restrict__ Ba1, unsigned short* __restrict__ Ba2,
    const unsigned short* __restrict__ x16,
    const unsigned int* __restrict__ eiw,
    int* __restrict__ flags, int* __restrict__ gcur)
{
  int b = blockIdx.x, t = threadIdx.x;
  __shared__ int sf, si;
  if (t == 0) { sf = 0; si = 1; }
  __syncthreads();
  int bad = 0;
  for (int i = t; i < 4096; i += 256) {
    float v = bf2f(x16[i]);
    if (!(v == v) || fabsf(v) > 100.f) bad = 1;
  }
  if (bad) atomicOr(&sf, 1);
  if (b == 0 && t < 128 && eiw[2 * t + 1] != 0u) atomicAnd(&si, 0);
  __syncthreads();
  int f32 = sf;
  if (b == 0 && t == 0) { flags[0] = sf; flags[1] = si; }
  if (b == 0 && t < NBUCK) gcur[t] = t * CAP;   // re-init every launch

  if (b < 8) {
    int g = b * 256 + t;          // 0..2047
    int l = g >> 10;
    int rem = g & 1023;
    int k = rem >> 3, n = rem & 7;
    const void* W  = l ? W2 : W1;
    const void* av = (n < 4) ? (l ? as2 : as1) : (l ? ad2 : ad1);
    int h = n & 3;
    float sum = 0.f;
    for (int c = 0; c < 32; c++) {
      float w = f32 ? ((const float*)W)[k * 128 + h * 32 + c]
                    : bf2f(((const unsigned short*)W)[k * 128 + h * 32 + c]);
      float a = f32 ? ((const float*)av)[h * 32 + c]
                    : bf2f(((const unsigned short*)av)[h * 32 + c]);
      sum += w * a;
    }
    unsigned short* Ba = l ? Ba2 : Ba1;
    Ba[n * 128 + k] = f2bf(sum);
    Ba[(8 + (rem >> 7)) * 128 + (rem & 127)] = 0;   // zero rows 8..15
  } else {
    int b2 = b - 8;
    int l = b2 >> 7, c = b2 & 127;
    if (t < 128) {
      const void* W = l ? W2 : W1;
      unsigned short* Wt = l ? Wt2 : Wt1;
      Wt[c * 128 + t] = f32 ? f2bf(((const float*)W)[t * 128 + c])
                            : ((const unsigned short*)W)[t * 128 + c];
    }
  }
}

// ---- shared GEMM body: 128-row tiles, each B-frag feeds 2 MFMAs ---------
struct SmemG { unsigned short WB[144][136]; };

static __device__ __forceinline__ void gemm_body(
    SmemG& sm, int bx,
    const void* __restrict__ X,
    const unsigned short* __restrict__ Wt_g,
    const unsigned short* __restrict__ Ba_g,
    unsigned short* __restrict__ H, float* __restrict__ AS,
    float* __restrict__ AD, int nrows, int xf32)
{
  int tid = threadIdx.x;
#pragma unroll
  for (int i = 0; i < 8; i++) {
    int j = i * 256 + tid;        // 2048 16B chunks of W^T
    int c = j >> 4, k8 = j & 15;
    *(short8*)&sm.WB[c][k8 * 8] = *(const short8*)(Wt_g + c * 128 + k8 * 8);
  }
  {
    int n = tid >> 4, k8 = tid & 15;   // Ba rows 128..143 (8..15 zeroed)
    *(short8*)&sm.WB[128 + n][k8 * 8] = *(const short8*)(Ba_g + n * 128 + k8 * 8);
  }
  __syncthreads();
  int wave = tid >> 6, lane = tid & 63;
  int R0 = (bx * 4 + wave) * 32;
  if (R0 >= nrows) return;
  int m = lane & 15, quad = lane >> 4;
  int rA = R0 + m;        if (rA >= nrows) rA = nrows - 1;   // clamp: last tile only
  int rB = R0 + 16 + m;   if (rB >= nrows) rB = nrows - 1;
  size_t aA = (size_t)rA * CH + quad * 8;
  size_t aB = (size_t)rB * CH + quad * 8;
  float4v acc[2][8];
  float4v accA[2];
#pragma unroll
  for (int hf = 0; hf < 2; hf++) {
    accA[hf] = (float4v){0.f, 0.f, 0.f, 0.f};
#pragma unroll
    for (int ct = 0; ct < 8; ct++) acc[hf][ct] = (float4v){0.f, 0.f, 0.f, 0.f};
  }
#pragma unroll
  for (int kb = 0; kb < 4; kb++) {
    short8 a0 = load_bf8(X, aA + kb * 32, xf32);
    short8 a1 = load_bf8(X, aB + kb * 32, xf32);
#pragma unroll
    for (int ct = 0; ct < 8; ct++) {
      short8 bb = *(const short8*)&sm.WB[ct * 16 + m][kb * 32 + quad * 8];
      acc[0][ct] = __builtin_amdgcn_mfma_f32_16x16x32_bf16(a0, bb, acc[0][ct], 0, 0, 0);
      acc[1][ct] = __builtin_amdgcn_mfma_f32_16x16x32_bf16(a1, bb, acc[1][ct], 0, 0, 0);
    }
    short8 bA = *(const short8*)&sm.WB[128 + m][kb * 32 + quad * 8];
    accA[0] = __builtin_amdgcn_mfma_f32_16x16x32_bf16(a0, bA, accA[0], 0, 0, 0);
    accA[1] = __builtin_amdgcn_mfma_f32_16x16x32_bf16(a1, bA, accA[1], 0, 0, 0);
  }
#pragma unroll
  for (int hf = 0; hf < 2; hf++) {
    int rbase = R0 + hf * 16 + quad * 4;
#pragma unroll
    for (int ct = 0; ct < 8; ct++) {
      int col = ct * 16 + m;
#pragma unroll
      for (int r = 0; r < 4; r++)
        H[(size_t)(rbase + r) * CH + col] = __half_as_ushort(__float2half(acc[hf][ct][r]));
    }
    if (m < 4) {
#pragma unroll
      for (int r = 0; r < 4; r++)
        AS[(size_t)(rbase + r) * 4 + m] = accA[hf][r];
    } else if (m < 8) {
#pragma unroll
      for (int r = 0; r < 4; r++)
        AD[(size_t)(rbase + r) * 4 + (m - 4)] = accA[hf][r];
    }
  }
}

// layer-2 GEMM (standalone; X2 always bf16)
__global__ __launch_bounds__(256, 2) void k_gemm(
    const void* __restrict__ X,
    const unsigned short* __restrict__ Wt_g,
    const unsigned short* __restrict__ Ba_g,
    unsigned short* __restrict__ H, float* __restrict__ AS, float* __restrict__ AD,
    int nrows)
{
  __shared__ SmemG sm;
  gemm_body(sm, blockIdx.x, X, Wt_g, Ba_g, H, AS, AD, nrows, 0);
}

// layer-1 GEMM fused with block-local counting-sort scatter.
// Each scatter block: LDS hist over 196 buckets -> one global atomicAdd per
// bucket reserves a contiguous chunk -> chunked writes into padded ebuf.
// (round-1 lesson: per-node global cursors = 15x write amplification from
// cross-XCD line bouncing; ~10-edge contiguous chunks avoid that.)
__global__ __launch_bounds__(256, 2) void k_gemm_scat(
    const void* __restrict__ X,
    const unsigned short* __restrict__ Wt_g,
    const unsigned short* __restrict__ Ba_g,
    unsigned short* __restrict__ H, float* __restrict__ AS, float* __restrict__ AD,
    int nrows, const int* __restrict__ ei, int* __restrict__ gcur,
    unsigned int* __restrict__ ebuf, const int* __restrict__ flags)
{
  __shared__ SmemG sm;          // gemm blocks only
  __shared__ int hist[NBUCK];   // scatter blocks only
  __shared__ int cur[NBUCK];
  if (blockIdx.x >= GEMMB) {
    int b = blockIdx.x - GEMMB;
    int t = threadIdx.x;
    if (t < NBUCK) hist[t] = 0;
    __syncthreads();
    int i64 = flags[1];
    int base = b * EBLK;
    int sA[8], dA[8];
#pragma unroll
    for (int k = 0; k < 8; k++) {
      int e = base + k * 256 + t;
      sA[k] = -1;
      if (e < E_TOT) {
        load_edge(ei, e, i64, sA[k], dA[k]);
        atomicAdd(&hist[dA[k] >> 8], 1);
      }
    }
    __syncthreads();
    if (t < NBUCK) {
      int c = hist[t];
      cur[t] = c ? atomicAdd(&gcur[t], c) : 0;   // reserve contiguous chunk
    }
    __syncthreads();
#pragma unroll
    for (int k = 0; k < 8; k++) {
      if (sA[k] >= 0) {
        int pos = atomicAdd(&cur[dA[k] >> 8], 1);   // LDS atomic
        ebuf[pos] = ((unsigned)sA[k] << 8) | (unsigned)(dA[k] & 255);
      }
    }
    return;
  }
  gemm_body(sm, blockIdx.x, X, Wt_g, Ba_g, H, AS, AD, nrows, flags[0]);
}

// per-bucket fine CSR -> rpdeg (int2) + ushort csr (padded bucket layout)
__global__ __launch_bounds__(256) void k_fine(
    const unsigned int* __restrict__ ebuf, const int* __restrict__ gcur,
    int2* __restrict__ rpdeg, unsigned short* __restrict__ csr)
{
  __shared__ int cnt[256], sh[256], cur[256];
  int q = blockIdx.x, t = threadIdx.x;
  int lo = q * CAP, hi = gcur[q];
  cnt[t] = 0;
  __syncthreads();
  for (int i = lo + t; i < hi; i += 256)
    atomicAdd(&cnt[ebuf[i] & 255u], 1);
  __syncthreads();
  int v = cnt[t];
  sh[t] = v;
  __syncthreads();
  for (int off = 1; off < 256; off <<= 1) {
    int u = (t >= off) ? sh[t - off] : 0;
    __syncthreads();
    sh[t] += u;
    __syncthreads();
  }
  int lp = sh[t] - v;
  int n = (q << 8) + t;
  if (n < N_NODES) rpdeg[n] = make_int2(lo + lp, v);
  cur[t] = lo + lp;
  __syncthreads();
  for (int i = lo + t; i < hi; i += 256) {
    unsigned p = ebuf[i];
    int slot = atomicAdd(&cur[p & 255u], 1);   // LDS atomic
    csr[slot] = (unsigned short)(p >> 8);
  }
}

// ---- fused gather-aggregate + softmax + epilogue ------------------------
__global__ __launch_bounds__(256) void k_agg(
    const int2* __restrict__ rpdeg,
    const unsigned short* __restrict__ csr,
    const __half* __restrict__ H,
    const float* __restrict__ AS, const float* __restrict__ AD,
    const void* __restrict__ b, void* __restrict__ Y,
    const int* __restrict__ flags, int layer)
{
  int tid = threadIdx.x;
  int node = blockIdx.x * 4 + (tid >> 6);
  if (node >= N_NODES) return;
  int lane = tid & 63;
  int h = lane >> 4;
  int c0 = 2 * lane;
  int2 rd = rpdeg[node];
  int start = rd.x, dg = rd.y;
  float adh = AD[(size_t)node * 4 + h];
  const __half2* __restrict__ H2 = (const __half2*)H;
  float accx = 0.f, accy = 0.f, den = 0.f;
  int last = start + dg - 1;      // dg >= 1 always (self-loop)
  for (int j = 0; j < dg; j += 16) {
    int sI[16];
#pragma unroll
    for (int u = 0; u < 16; u++) {
      int idx = start + j + u;
      sI[u] = (int)csr[idx <= last ? idx : last];
    }
    float2 vV[16];
#pragma unroll
    for (int u = 0; u < 16; u++)
      vV[u] = __half22float2(H2[sI[u] * 64 + lane]);
    float eV[16];
#pragma unroll
    for (int u = 0; u < 16; u++)
      eV[u] = AS[sI[u] * 4 + h] + adh;
#pragma unroll
    for (int u = 0; u < 16; u++) {
      float x = eV[u] > 0.f ? eV[u] : 0.2f * eV[u];
      float ex = (j + u < dg) ? __expf(x) : 0.f;
      accx += ex * vV[u].x;
      accy += ex * vV[u].y;
      den  += ex;
    }
  }
  float inv = 1.f / (den + 1e-16f);
  int f32 = flags[0];
  float b0 = f32 ? ((const float*)b)[c0]     : bf2f(((const unsigned short*)b)[c0]);
  float b1 = f32 ? ((const float*)b)[c0 + 1] : bf2f(((const unsigned short*)b)[c0 + 1]);
  float r0 = accx * inv + b0;
  float r1 = accy * inv + b1;
  size_t o = (size_t)node * CH + c0;
  if (layer == 1) {                 // relu + bf16 -> X2
    r0 = r0 > 0.f ? r0 : 0.f;
    r1 = r1 > 0.f ? r1 : 0.f;
    ushort2 w; w.x = f2bf(r0); w.y = f2bf(r1);
    *(ushort2*)((unsigned short*)Y + o) = w;
  } else if (f32) {
    float2 w; w.x = r0; w.y = r1;
    *(float2*)((float*)Y + o) = w;
  } else {
    ushort2 w; w.x = f2bf(r0); w.y = f2bf(r1);
    *(ushort2*)((unsigned short*)Y + o) = w;
  }
}

extern "C" void kernel_launch(void* const* d_in, const int* in_sizes, int n_in,
                              void* d_out, int out_size, void* d_ws, size_t ws_size,
                              hipStream_t stream)
{
  const void* x   = d_in[0];
  const int*  ei  = (const int*)d_in[1];
  const void* W1  = d_in[2];
  const void* as1 = d_in[3];
  const void* ad1 = d_in[4];
  const void* b1  = d_in[5];
  const void* W2  = d_in[6];
  const void* as2 = d_in[7];
  const void* ad2 = d_in[8];
  const void* b2  = d_in[9];

  char* ws = (char*)d_ws;
  unsigned short* H   = (unsigned short*)(ws);             // 12,845,056 B (fp16)
  float*  AS          = (float*)(ws + 12845056);           //    802,816 B
  float*  AD          = (float*)(ws + 13647872);           //    802,816 B
  unsigned short* X2  = (unsigned short*)(ws + 14450688);  // 12,845,056 B
  int2*   rpdeg       = (int2*)(ws + 27295744);            //    400,000 B
  unsigned short* csr = (unsigned short*)(ws + 27695744);  //  1,806,336 B (196*CAP)
  unsigned int* ebuf  = (unsigned int*)(ws + 29502080);    //  3,612,672 B (196*CAP*4)
  int*    gcur        = (int*)(ws + 33114752);             //        784 B
  int*    flags       = (int*)(ws + 33115648);             //         64 B
  unsigned short* Wt1 = (unsigned short*)(ws + 33116672);  //     32,768 B
  unsigned short* Wt2 = (unsigned short*)(ws + 33149440);  //     32,768 B
  unsigned short* Ba1 = (unsigned short*)(ws + 33182208);  //      4,096 B
  unsigned short* Ba2 = (unsigned short*)(ws + 33186304);  //      4,096 B

  const int agg_blocks = (N_NODES + 3) / 4;                // 1 wave per node

  // prep: detect + W transpose + Ba + gcur init (fused, 1 launch)
  k_prep<<<264, 256, 0, stream>>>(W1, W2, as1, ad1, as2, ad2,
                                  Wt1, Wt2, Ba1, Ba2,
                                  (const unsigned short*)x,
                                  (const unsigned int*)ei, flags, gcur);

  // layer-1 GEMM overlapped with bucket scatter (single edge pass)
  k_gemm_scat<<<GEMMB + NEB, 256, 0, stream>>>(
      x, Wt1, Ba1, H, AS, AD, N_NODES, ei, gcur, ebuf, flags);

  // per-bucket fine CSR (padded layout, no global scans needed)
  k_fine<<<NBUCK, 256, 0, stream>>>(ebuf, gcur, rpdeg, csr);

  // layer 1 aggregate
  k_agg<<<agg_blocks, 256, 0, stream>>>(rpdeg, csr,
                                        (const __half*)H, AS, AD,
                                        b1, X2, flags, 1);

  // layer 2
  k_gemm<<<GEMMB, 256, 0, stream>>>(X2, Wt2, Ba2, H, AS, AD, N_NODES);
  k_agg<<<agg_blocks, 256, 0, stream>>>(rpdeg, csr,
                                        (const __half*)H, AS, AD,
                                        b2, d_out, flags, 2);
}